// Round 13
// baseline (387.567 us; speedup 1.0000x reference)
//
#include <hip/hip_runtime.h>
#include <hip/hip_bf16.h>
#include <cstdint>
#include <cstddef>

// ---------------------------------------------------------------------------
// PrefillDecoderLayer on MI355X (gfx950).
// Fat GEMMs (qkv/wkv/ff1): 128x256 tile, 8 waves, BK=64, 48KB LDS.
// Narrow GEMMs (wo_*/wq/ff2): 128x64 tile, 4 waves, 24KB LDS, NO split-K
// (512 wg = 2 blocks/CU), residual/bf16 fused in epilogue.
// All single-buffered, hoisted staging, XOR-swizzled LDS, banded XCD swizzle.
// Flash attention v6 (KVBLK=64, raw-score max + folded scale, v_max3,
// defer-max, head-banded XCD locality); SA unpaired 512 blocks heavy-first.
// ---------------------------------------------------------------------------

typedef __attribute__((ext_vector_type(4))) float f32x4;
typedef __attribute__((ext_vector_type(8))) short s8v;   // 8 bf16 as raw bits
typedef __attribute__((ext_vector_type(2))) unsigned uint2v;

#define DEVI __device__ __forceinline__

DEVI short f2bf(float f) {  // RNE float -> bf16 bits
  union { float f; unsigned u; } x; x.f = f;
  unsigned r = x.u + 0x7fffu + ((x.u >> 16) & 1u);
  return (short)(r >> 16);
}
DEVI unsigned cvtpk_bf2(float lo, float hi) {  // v_cvt_pk_bf16_f32 (RNE)
  unsigned r;
  asm("v_cvt_pk_bf16_f32 %0, %1, %2" : "=v"(r) : "v"(lo), "v"(hi));
  return r;
}
DEVI float fexp2(float x) {
  float r;
  asm("v_exp_f32 %0, %1" : "=v"(r) : "v"(x));
  return r;
}
DEVI float fmax3(float a, float b, float c) {
  float r;
  asm("v_max3_f32 %0, %1, %2, %3" : "=v"(r) : "v"(a), "v"(b), "v"(c));
  return r;
}
DEVI float bpermf(int srclane, float v) {
  union { float f; int i; } x; x.f = v;
  x.i = __builtin_amdgcn_ds_bpermute(srclane << 2, x.i);
  return x.f;
}
DEVI void gload_lds16(const void* g, void* l) {
  __builtin_amdgcn_global_load_lds((const __attribute__((address_space(1))) void*)g,
                                   (__attribute__((address_space(3))) void*)l,
                                   16, 0, 0);
}

// banded XCD swizzle: XCD-major linear id, 8-wide bx bands, col-major
DEVI void xcd_swizzle(int& bx, int& by) {
  int gx = gridDim.x, gy = gridDim.y;
  int nxy = gx * gy, chunk = nxy >> 3;
  int orig = blockIdx.y * gx + blockIdx.x;
  int gid = (orig & 7) * chunk + (orig >> 3);
  int full = gy << 3, nfull = gx >> 3, lim = nfull * full;
  if (gid < lim) {
    int band = gid / full, r = gid - band * full;
    bx = (band << 3) + (r & 7);
    by = r >> 3;
  } else {
    int r = gid - lim, w = gx - (nfull << 3);
    bx = (nfull << 3) + r % w;
    by = r / w;
  }
}

// ---------------------------------------------------------------------------
// Prep uber-kernel: 7 weight transposes (fp32 KxN -> bf16 NxK) + maskpack.
// ---------------------------------------------------------------------------
__global__ __launch_bounds__(256) void k_prep(
    const float* __restrict__ wqkv, const float* __restrict__ wosa,
    const float* __restrict__ wq,   const float* __restrict__ wkv,
    const float* __restrict__ woxa, const float* __restrict__ wff1,
    const float* __restrict__ wff2,
    short* __restrict__ wqkv_t, short* __restrict__ wosa_t,
    short* __restrict__ wq_t,   short* __restrict__ wkv_t,
    short* __restrict__ woxa_t, short* __restrict__ wff1_t,
    short* __restrict__ wff2_t,
    const int* __restrict__ mask, unsigned long long* __restrict__ mbits) {
  int id = blockIdx.x;
  const float* w; short* wt; int K, N, tx, r;
  if (id < 3072)       { w = wqkv; wt = wqkv_t; K = 1024; N = 3072; tx = 96;  r = id; }
  else if (id < 4096)  { w = wosa; wt = wosa_t; K = 1024; N = 1024; tx = 32;  r = id - 3072; }
  else if (id < 5120)  { w = wq;   wt = wq_t;   K = 1024; N = 1024; tx = 32;  r = id - 4096; }
  else if (id < 7168)  { w = wkv;  wt = wkv_t;  K = 1024; N = 2048; tx = 64;  r = id - 5120; }
  else if (id < 8192)  { w = woxa; wt = woxa_t; K = 1024; N = 1024; tx = 32;  r = id - 7168; }
  else if (id < 12288) { w = wff1; wt = wff1_t; K = 1024; N = 4096; tx = 128; r = id - 8192; }
  else if (id < 16384) { w = wff2; wt = wff2_t; K = 4096; N = 1024; tx = 32;  r = id - 12288; }
  else {
    int t = threadIdx.x;
    if (t < 96) {
      int b = t / 24, wd = t % 24;
      unsigned long long v = 0;
      const int* mb = mask + (size_t)b * 1500;
      for (int j = 0; j < 64; j++) {
        int k = wd * 64 + j;
        if (k < 1500 && mb[k]) v |= (1ull << j);
      }
      mbits[b * 24 + wd] = v;
    }
    return;
  }
  __shared__ float tile[32][33];
  int n0 = (r % tx) * 32, k0 = (r / tx) * 32;
  int t = threadIdx.x;
  int row = t >> 3, c4 = (t & 7) * 4;
  *(f32x4*)&tile[row][c4] = *(const f32x4*)(w + (size_t)(k0 + row) * N + n0 + c4);
  __syncthreads();
  float v0 = tile[c4 + 0][row], v1 = tile[c4 + 1][row];
  float v2 = tile[c4 + 2][row], v3 = tile[c4 + 3][row];
  uint2v o = {cvtpk_bf2(v0, v1), cvtpk_bf2(v2, v3)};
  *(uint2v*)(wt + (size_t)(n0 + row) * K + k0 + c4) = o;
}

// ---------------------------------------------------------------------------
// Per-head V transpose: src[b*T+t][coff+h*64+d] -> dst[(b*16+h)][64][Tp]
// ---------------------------------------------------------------------------
__global__ __launch_bounds__(256) void k_vtrans(
    const short* __restrict__ src, int srs, int coff,
    short* __restrict__ dst, int T, int Tp) {
  __shared__ short tile[32][72];
  int bh = blockIdx.y, b = bh >> 4, h = bh & 15;
  int t0 = blockIdx.x * 32;
  const short* sB = src + (size_t)b * T * srs + coff + h * 64;
  short* dB = dst + (size_t)bh * 64 * Tp;
  int t = threadIdx.x;
  int r = t >> 3, c = (t & 7) * 8;
  int tr = t0 + r; if (tr > T - 1) tr = T - 1;
  *(s8v*)&tile[r][c] = *(const s8v*)(sB + (size_t)tr * srs + c);
  __syncthreads();
  int d = t & 63, ch = t >> 6;
  s8v o;
#pragma unroll
  for (int j = 0; j < 8; j++) o[j] = tile[ch * 8 + j][d];
  *(s8v*)(dB + (size_t)d * Tp + t0 + ch * 8) = o;
}

// ---------------------------------------------------------------------------
// Dual LayerNorm (x: 4096 rows -> xn; enc: 6000 rows -> mn), D=1024.
// ---------------------------------------------------------------------------
__global__ __launch_bounds__(256) void k_ln2(
    const float* __restrict__ x, const float* __restrict__ gx,
    short* __restrict__ ox,
    const float* __restrict__ e, const float* __restrict__ ge,
    short* __restrict__ oe) {
  int id = blockIdx.x;
  const float* src; const float* g; short* dst; int row;
  if (id < 4096) { src = x; g = gx; dst = ox; row = id; }
  else           { src = e; g = ge; dst = oe; row = id - 4096; }
  const float* xr = src + (size_t)row * 1024;
  int t = threadIdx.x, wid = t >> 6, lane = t & 63;
  f32x4 v = ((const f32x4*)xr)[t];
  float s = v[0] + v[1] + v[2] + v[3];
#pragma unroll
  for (int m = 32; m >= 1; m >>= 1) s += __shfl_xor(s, m);
  __shared__ float red[4];
  if (lane == 0) red[wid] = s;
  __syncthreads();
  float mean = (red[0] + red[1] + red[2] + red[3]) * (1.f / 1024.f);
  float q = 0.f;
#pragma unroll
  for (int i = 0; i < 4; i++) { v[i] -= mean; q += v[i] * v[i]; }
#pragma unroll
  for (int m = 32; m >= 1; m >>= 1) q += __shfl_xor(q, m);
  __syncthreads();
  if (lane == 0) red[wid] = q;
  __syncthreads();
  float var = (red[0] + red[1] + red[2] + red[3]) * (1.f / 1024.f);
  float rs = rsqrtf(var + 1e-5f);
  f32x4 gv = ((const f32x4*)g)[t];
  uint2v w = {cvtpk_bf2(v[0] * rs * gv[0], v[1] * rs * gv[1]),
              cvtpk_bf2(v[2] * rs * gv[2], v[3] * rs * gv[3])};
  *(uint2v*)(dst + (size_t)row * 1024 + t * 4) = w;
}

// single LayerNorm, D=1024, fp32 -> bf16
__global__ __launch_bounds__(256) void k_ln(
    const float* __restrict__ x, const float* __restrict__ g,
    short* __restrict__ out) {
  int row = blockIdx.x;
  const float* xr = x + (size_t)row * 1024;
  int t = threadIdx.x, wid = t >> 6, lane = t & 63;
  f32x4 v = ((const f32x4*)xr)[t];
  float s = v[0] + v[1] + v[2] + v[3];
#pragma unroll
  for (int m = 32; m >= 1; m >>= 1) s += __shfl_xor(s, m);
  __shared__ float red[4];
  if (lane == 0) red[wid] = s;
  __syncthreads();
  float mean = (red[0] + red[1] + red[2] + red[3]) * (1.f / 1024.f);
  float q = 0.f;
#pragma unroll
  for (int i = 0; i < 4; i++) { v[i] -= mean; q += v[i] * v[i]; }
#pragma unroll
  for (int m = 32; m >= 1; m >>= 1) q += __shfl_xor(q, m);
  __syncthreads();
  if (lane == 0) red[wid] = q;
  __syncthreads();
  float var = (red[0] + red[1] + red[2] + red[3]) * (1.f / 1024.f);
  float rs = rsqrtf(var + 1e-5f);
  f32x4 gv = ((const f32x4*)g)[t];
  uint2v w = {cvtpk_bf2(v[0] * rs * gv[0], v[1] * rs * gv[1]),
              cvtpk_bf2(v[2] * rs * gv[2], v[3] * rs * gv[3])};
  *(uint2v*)(out + (size_t)row * 1024 + t * 4) = w;
}

// ---------------------------------------------------------------------------
// GEMM v4 (fat): 128x256 tile, BK=64, 8 waves (2Mx4N), 48KB LDS (3 blk/CU).
// ---------------------------------------------------------------------------
template <bool GELU_, bool F32OUT, bool BF16OUT, bool KV>
__global__ __launch_bounds__(512) void k_gemm4(
    const short* __restrict__ A, const short* __restrict__ Bt,
    float* __restrict__ Cf, short* __restrict__ Cb,
    float* __restrict__ okv, int M, int N, int K, int lda, int ldb) {
  __shared__ short As[128 * 64];   // 16 KB
  __shared__ short Bs[256 * 64];   // 32 KB

  int bx, by;
  xcd_swizzle(bx, by);
  int am = bx * 128, bn = by * 256;

  int t = threadIdx.x, wid = t >> 6, lane = t & 63;
  int la = lane & 15, lb = lane >> 4;
  int wr = wid >> 2, wc = wid & 3;

  const short* gpA[2]; const short* gpB[4];
  int dofA[2], dofB[4];
#pragma unroll
  for (int l = 0; l < 2; l++) {
    int c = l * 512 + t;
    int row = c >> 3, g = c & 7;
    int ar = am + row; if (ar > M - 1) ar = M - 1;
    gpA[l] = A + (size_t)ar * lda + ((g ^ (row & 7)) << 3);
    dofA[l] = (l * 512 + wid * 64) * 8;
  }
#pragma unroll
  for (int l = 0; l < 4; l++) {
    int c = l * 512 + t;
    int row = c >> 3, g = c & 7;
    gpB[l] = Bt + (size_t)(bn + row) * ldb + ((g ^ (row & 7)) << 3);
    dofB[l] = (l * 512 + wid * 64) * 8;
  }

  int aOff[4], bOff[4];
#pragma unroll
  for (int m = 0; m < 4; m++) {
    int r = wr * 64 + m * 16 + la;
    aOff[m] = r * 64 + ((lb ^ (r & 7)) << 3);
  }
#pragma unroll
  for (int n = 0; n < 4; n++) {
    int r = wc * 64 + n * 16 + la;
    bOff[n] = r * 64 + ((lb ^ (r & 7)) << 3);
  }

  f32x4 acc[4][4];
#pragma unroll
  for (int m = 0; m < 4; m++)
#pragma unroll
    for (int n = 0; n < 4; n++) acc[m][n] = (f32x4){0.f, 0.f, 0.f, 0.f};

  int nk = K >> 6;
  for (int ks = 0; ks < nk; ++ks) {
#pragma unroll
    for (int l = 0; l < 2; l++) { gload_lds16(gpA[l], As + dofA[l]); gpA[l] += 64; }
#pragma unroll
    for (int l = 0; l < 4; l++) { gload_lds16(gpB[l], Bs + dofB[l]); gpB[l] += 64; }
    __syncthreads();
#pragma unroll
    for (int kk = 0; kk < 2; kk++) {
      s8v af[4], bfg[4];
#pragma unroll
      for (int m = 0; m < 4; m++)
        af[m] = *(const s8v*)(As + (aOff[m] ^ (kk << 5)));
#pragma unroll
      for (int n = 0; n < 4; n++)
        bfg[n] = *(const s8v*)(Bs + (bOff[n] ^ (kk << 5)));
#pragma unroll
      for (int m = 0; m < 4; m++)
#pragma unroll
        for (int n = 0; n < 4; n++)
          acc[m][n] = __builtin_amdgcn_mfma_f32_16x16x32_bf16(af[m], bfg[n], acc[m][n], 0, 0, 0);
    }
    __syncthreads();
  }

#pragma unroll
  for (int m = 0; m < 4; m++) {
    int rb = am + wr * 64 + m * 16 + lb * 4;
#pragma unroll
    for (int n = 0; n < 4; n++) {
      int col = bn + wc * 64 + n * 16 + la;
#pragma unroll
      for (int j = 0; j < 4; j++) {
        int r = rb + j;
        if (r < M) {
          float v = acc[m][n][j];
          if (GELU_) {
            float u = v;
            float y = 0.7978845608f * u * (1.f + 0.044715f * u * u);
            float e = fexp2(fminf(y * 2.88539008f, 80.f));  // e^{2y}
            float th = (e - 1.f) * __builtin_amdgcn_rcpf(e + 1.f);
            v = 0.5f * u * (1.f + th);
          }
          if (F32OUT) Cf[(size_t)r * N + col] = v;
          if (BF16OUT) Cb[(size_t)r * N + col] = f2bf(v);
          if (KV) {  // fused fp32 k/v export (qkv GEMM)
            if (col >= 2048)
              okv[(size_t)4096 * 1024 + (size_t)r * 1024 + (col - 2048)] = v;
            else if (col >= 1024)
              okv[(size_t)r * 1024 + (col - 1024)] = v;
          }
        }
      }
    }
  }
}

// ---------------------------------------------------------------------------
// GEMM v5 (narrow): 128x64 tile, BK=64, 4 waves (2Mx2N, 64x32 wave tile),
// 24KB LDS, NO split-K. Residual / bf16-out fused in epilogue.
// ---------------------------------------------------------------------------
template <bool RES, bool F32OUT, bool BF16OUT>
__global__ __launch_bounds__(256) void k_gemm5(
    const short* __restrict__ A, const short* __restrict__ Bt,
    float* __restrict__ Cf, short* __restrict__ Cb,
    const float* __restrict__ res, int M, int N, int K, int lda, int ldb) {
  __shared__ short As[128 * 64];   // 16 KB
  __shared__ short Bs[64 * 64];    //  8 KB

  int bx, by;
  xcd_swizzle(bx, by);
  int am = bx * 128, bn = by * 64;

  int t = threadIdx.x, wid = t >> 6, lane = t & 63;
  int la = lane & 15, lb = lane >> 4;
  int wr = wid >> 1, wc = wid & 1;

  const short* gpA[4]; const short* gpB[2];
  int dofA[4], dofB[2];
#pragma unroll
  for (int l = 0; l < 4; l++) {
    int cl = l * 256 + t;
    int row = cl >> 3, g = cl & 7;
    int ar = am + row; if (ar > M - 1) ar = M - 1;
    gpA[l] = A + (size_t)ar * lda + ((g ^ (row & 7)) << 3);
    dofA[l] = (l * 256 + wid * 64) * 8;
  }
#pragma unroll
  for (int l = 0; l < 2; l++) {
    int cl = l * 256 + t;
    int row = cl >> 3, g = cl & 7;
    gpB[l] = Bt + (size_t)(bn + row) * ldb + ((g ^ (row & 7)) << 3);
    dofB[l] = (l * 256 + wid * 64) * 8;
  }

  int aOff[4], bOff[2];
#pragma unroll
  for (int m = 0; m < 4; m++) {
    int r = wr * 64 + m * 16 + la;
    aOff[m] = r * 64 + ((lb ^ (r & 7)) << 3);
  }
#pragma unroll
  for (int n = 0; n < 2; n++) {
    int r = wc * 32 + n * 16 + la;
    bOff[n] = r * 64 + ((lb ^ (r & 7)) << 3);
  }

  f32x4 acc[4][2];
#pragma unroll
  for (int m = 0; m < 4; m++)
#pragma unroll
    for (int n = 0; n < 2; n++) acc[m][n] = (f32x4){0.f, 0.f, 0.f, 0.f};

  int nk = K >> 6;
  for (int ks = 0; ks < nk; ++ks) {
#pragma unroll
    for (int l = 0; l < 4; l++) { gload_lds16(gpA[l], As + dofA[l]); gpA[l] += 64; }
#pragma unroll
    for (int l = 0; l < 2; l++) { gload_lds16(gpB[l], Bs + dofB[l]); gpB[l] += 64; }
    __syncthreads();
#pragma unroll
    for (int kk = 0; kk < 2; kk++) {
      s8v af[4], bfg[2];
#pragma unroll
      for (int m = 0; m < 4; m++)
        af[m] = *(const s8v*)(As + (aOff[m] ^ (kk << 5)));
#pragma unroll
      for (int n = 0; n < 2; n++)
        bfg[n] = *(const s8v*)(Bs + (bOff[n] ^ (kk << 5)));
#pragma unroll
      for (int m = 0; m < 4; m++)
#pragma unroll
        for (int n = 0; n < 2; n++)
          acc[m][n] = __builtin_amdgcn_mfma_f32_16x16x32_bf16(af[m], bfg[n], acc[m][n], 0, 0, 0);
    }
    __syncthreads();
  }

#pragma unroll
  for (int m = 0; m < 4; m++) {
    int rb = am + wr * 64 + m * 16 + lb * 4;
#pragma unroll
    for (int n = 0; n < 2; n++) {
      int col = bn + wc * 32 + n * 16 + la;
#pragma unroll
      for (int j = 0; j < 4; j++) {
        int r = rb + j;
        if (r < M) {
          float v = acc[m][n][j];
          if (RES) v += res[(size_t)r * N + col];
          if (F32OUT) Cf[(size_t)r * N + col] = v;
          if (BF16OUT) Cb[(size_t)r * N + col] = f2bf(v);
        }
      }
    }
  }
}

// ---------------------------------------------------------------------------
// Flash attention v6. 512 thr = 8 waves x 16 q-rows = 128 q/block.
// CAUSAL: 512 blocks, ONE supertile each, heavy-first (st = 7 - qsel).
// XA: 512 blocks (qsel 0..7). Raw-score max + folded scale, v_max3 tree,
// defer-max, head-banded XCD locality.
// ---------------------------------------------------------------------------
template <bool CAUSAL>
__global__ __launch_bounds__(512) void k_attn4(
    const short* __restrict__ qbuf, int qrs,
    const short* __restrict__ kbuf, int krs,
    const short* __restrict__ vT, int vts,
    short* __restrict__ obuf, int ors,
    const unsigned long long* __restrict__ mbits, int mwords,
    int Tq, int Tk, float scale) {
  __shared__ short Ks[64 * 64];
  __shared__ short Vs[64 * 64];
  __shared__ short Ps[8 * 1024];
  int lid = blockIdx.y * gridDim.x + blockIdx.x;
  int rest = lid >> 3;
  int bh = (lid & 7) * 8 + (rest & 7);
  int qsel = rest >> 3;                 // 0..7
  int st = CAUSAL ? (7 - qsel) : qsel;  // heavy supertiles dispatch first
  int b = bh >> 4, h = bh & 15;
  int t = threadIdx.x, wid = t >> 6, lane = t & 63;
  int la = lane & 15, lb = lane >> 4;
  float lscale = scale * 1.44269504f;   // log2 domain

  const short* qB = qbuf + (size_t)b * Tq * qrs + h * 64;
  const short* kB = kbuf + (size_t)b * Tk * krs + h * 64;
  const short* vB = vT + (size_t)bh * 64 * vts;
  char* Pw = (char*)(Ps + wid * 1024);

  int sr = t >> 3, scol = (t & 7) * 8;
  int swz = sr * 64 + (scol ^ ((sr & 7) << 3));

  int q0 = st * 128 + wid * 16;
  int nkt = CAUSAL ? 2 * st + 2 : (Tk + 63) >> 6;
  int lastkt = CAUSAL ? (q0 >> 6) : nkt - 1;

  s8v qf[2];
#pragma unroll
  for (int kk = 0; kk < 2; kk++)
    qf[kk] = *(const s8v*)(qB + (size_t)(q0 + la) * qrs + kk * 32 + lb * 8);

  f32x4 accO[4];
#pragma unroll
  for (int n = 0; n < 4; n++) accO[n] = (f32x4){0.f, 0.f, 0.f, 0.f};
  float m = -1e30f, l = 0.f;

  s8v krg, vrg;
  {
    int tk = sr; if (tk > Tk - 1) tk = Tk - 1;
    krg = *(const s8v*)(kB + (size_t)tk * krs + scol);
    vrg = *(const s8v*)(vB + (size_t)sr * vts + scol);
  }

  for (int kt = 0; kt < nkt; kt++) {
    int kb0 = kt << 6;
    __syncthreads();
    *(s8v*)&Ks[swz] = krg;
    *(s8v*)&Vs[swz] = vrg;
    __syncthreads();
    if (kt + 1 < nkt) {
      int kb = kb0 + 64;
      int tk = kb + sr; if (tk > Tk - 1) tk = Tk - 1;
      krg = *(const s8v*)(kB + (size_t)tk * krs + scol);
      vrg = *(const s8v*)(vB + (size_t)sr * vts + kb + scol);
    }
    if (kt > lastkt) continue;

    bool needMask;
    unsigned long long wm = ~0ull;
    if (CAUSAL) {
      needMask = (kt == lastkt);
    } else {
      wm = mbits[(size_t)b * mwords + kt];
      needMask = (wm != ~0ull);
    }

    // QK^T raw scores: lane holds S_raw[q=la][k=16n+lb*4+j]
    float sc[4][4];
    __builtin_amdgcn_s_setprio(1);
#pragma unroll
    for (int n = 0; n < 4; n++) {
      f32x4 a = (f32x4){0.f, 0.f, 0.f, 0.f};
#pragma unroll
      for (int kk = 0; kk < 2; kk++) {
        s8v kf = *(const s8v*)&Ks[(n * 16 + la) * 64 +
                                  ((kk * 32 + lb * 8) ^ ((la & 7) << 3))];
        a = __builtin_amdgcn_mfma_f32_16x16x32_bf16(kf, qf[kk], a, 0, 0, 0);
      }
      if (needMask) {
#pragma unroll
        for (int j = 0; j < 4; j++) {
          int ki = n * 16 + lb * 4 + j;
          bool ok = CAUSAL ? (kb0 + ki <= q0 + la) : (((wm >> ki) & 1ull) != 0);
          sc[n][j] = ok ? a[j] : -1e30f;
        }
      } else {
#pragma unroll
        for (int j = 0; j < 4; j++) sc[n][j] = a[j];
      }
    }
    __builtin_amdgcn_s_setprio(0);

    // raw-score max via v_max3 tree; scale applied once after reduce
    float rn[4];
#pragma unroll
    for (int n = 0; n < 4; n++)
      rn[n] = fmaxf(fmax3(sc[n][0], sc[n][1], sc[n][2]), sc[n][3]);
    float tm = fmaxf(fmax3(rn[0], rn[1], rn[2]), rn[3]);
    tm = fmaxf(tm, __shfl_xor(tm, 16));
    tm = fmaxf(tm, __shfl_xor(tm, 32));
    tm = fmaxf(tm * lscale, -1e4f);

    bool skip = __all(tm - m <= 10.f);  // defer-max (T13)
    float alpha = 1.f;
    if (!skip) {
      float mn_ = fmaxf(m, tm);
      alpha = fexp2(m - mn_);
      m = mn_;
    }
    float nm = -m;

    unsigned W[4][2];
    float ps = 0.f;
#pragma unroll
    for (int n = 0; n < 4; n++) {
      float p0 = fexp2(__builtin_fmaf(sc[n][0], lscale, nm));
      float p1 = fexp2(__builtin_fmaf(sc[n][1], lscale, nm));
      float p2 = fexp2(__builtin_fmaf(sc[n][2], lscale, nm));
      float p3 = fexp2(__builtin_fmaf(sc[n][3], lscale, nm));
      ps += (p0 + p1) + (p2 + p3);
      W[n][0] = cvtpk_bf2(p0, p1);
      W[n][1] = cvtpk_bf2(p2, p3);
    }
    ps += __shfl_xor(ps, 16);
    ps += __shfl_xor(ps, 32);
    l = l * alpha + ps;

    if (!skip) {
#pragma unroll
      for (int j = 0; j < 4; j++) {
        float aj = bpermf(lb * 20 + j, alpha);
#pragma unroll
        for (int n = 0; n < 4; n++) accO[n][j] *= aj;
      }
    }

#pragma unroll
    for (int n = 0; n < 4; n++) {
      uint2v w2 = {W[n][0], W[n][1]};
      *(uint2v*)(Pw + ((la * 128 + n * 32 + lb * 8) ^ ((la & 7) << 4))) = w2;
    }
    __builtin_amdgcn_s_setprio(1);
#pragma unroll
    for (int kk = 0; kk < 2; kk++) {
      s8v pa = *(const s8v*)(Pw + ((la * 128 + kk * 64 + lb * 16) ^ ((la & 7) << 4)));
#pragma unroll
      for (int n = 0; n < 4; n++) {
        s8v vf = *(const s8v*)&Vs[(n * 16 + la) * 64 +
                                  ((kk * 32 + lb * 8) ^ ((la & 7) << 3))];
        accO[n] = __builtin_amdgcn_mfma_f32_16x16x32_bf16(pa, vf, accO[n], 0, 0, 0);
      }
    }
    __builtin_amdgcn_s_setprio(0);
  }

#pragma unroll
  for (int j = 0; j < 4; j++) {
    float lj = bpermf(lb * 20 + j, l);
    float inv = 1.f / lj;
    int r = q0 + lb * 4 + j;
#pragma unroll
    for (int n = 0; n < 4; n++)
      obuf[(size_t)(b * Tq + r) * ors + h * 64 + n * 16 + la] = f2bf(accO[n][j] * inv);
  }
}

// ---------------------------------------------------------------------------
extern "C" void kernel_launch(void* const* d_in, const int* in_sizes, int n_in,
                              void* d_out, int out_size, void* d_ws, size_t ws_size,
                              hipStream_t stream) {
  (void)in_sizes; (void)n_in; (void)out_size; (void)ws_size;
  const float* x      = (const float*)d_in[0];
  const float* enc    = (const float*)d_in[1];
  const int*   mask   = (const int*)d_in[2];
  const float* w_qkv  = (const float*)d_in[3];
  const float* w_o_sa = (const float*)d_in[4];
  const float* w_q    = (const float*)d_in[5];
  const float* w_kv   = (const float*)d_in[6];
  const float* w_o_xa = (const float*)d_in[7];
  const float* w_ff1  = (const float*)d_in[8];
  const float* w_ff2  = (const float*)d_in[9];
  const float* g_sa   = (const float*)d_in[10];
  const float* g_xaq  = (const float*)d_in[11];
  const float* g_xam  = (const float*)d_in[12];
  const float* g_ff   = (const float*)d_in[13];

  float* out_x = (float*)d_out;
  float* out_k = out_x + (size_t)4096 * 1024;

  char* ws = (char*)d_ws;
  size_t off = 0;
  auto alloc = [&](size_t bytes) -> void* {
    void* p = ws + off;
    off += (bytes + 255) & ~(size_t)255;
    return p;
  };
  short* wqkv_t = (short*)alloc((size_t)3072 * 1024 * 2);
  short* wosa_t = (short*)alloc((size_t)1024 * 1024 * 2);
  short* wq_t   = (short*)alloc((size_t)1024 * 1024 * 2);
  short* wkv_t  = (short*)alloc((size_t)2048 * 1024 * 2);
  short* woxa_t = (short*)alloc((size_t)1024 * 1024 * 2);
  short* wff1_t = (short*)alloc((size_t)4096 * 1024 * 2);
  short* wff2_t = (short*)alloc((size_t)1024 * 4096 * 2);
  short* xn     = (short*)alloc((size_t)4096 * 1024 * 2);  // reused as vTsa
  short* qkv_b  = (short*)alloc((size_t)4096 * 3072 * 2);
  short* sa_b   = (short*)alloc((size_t)4096 * 1024 * 2);
  float* x1     = (float*)alloc((size_t)4096 * 1024 * 4);
  short* qn     = (short*)alloc((size_t)4096 * 1024 * 2);
  short* mn     = (short*)alloc((size_t)6000 * 1024 * 2);
  short* qx_b   = (short*)alloc((size_t)4096 * 1024 * 2);
  short* kvx_b  = (short*)alloc((size_t)6000 * 2048 * 2);
  short* xa_b   = (short*)alloc((size_t)4096 * 1024 * 2);
  float* x2     = (float*)alloc((size_t)4096 * 1024 * 4);
  short* hn     = (short*)alloc((size_t)4096 * 1024 * 2);
  short* h1     = (short*)alloc((size_t)4096 * 4096 * 2);  // first 12.6MB = vTxa
  unsigned long long* mbits = (unsigned long long*)alloc(4 * 24 * 8);

  short* vTsa = xn;            // [64 bh][64][1024]
  short* vTxa = h1;            // [64 bh][64][1536]

  // prep: all weight transposes + maskpack in one launch
  k_prep<<<16385, 256, 0, stream>>>(
      w_qkv, w_o_sa, w_q, w_kv, w_o_xa, w_ff1, w_ff2,
      wqkv_t, wosa_t, wq_t, wkv_t, woxa_t, wff1_t, wff2_t, mask, mbits);
  // LN(x) + LN(enc) in one launch
  k_ln2<<<10096, 256, 0, stream>>>(x, g_sa, xn, enc, g_xam, mn);

  // --- self-attention block ---
  k_gemm4<false, false, true, true><<<dim3(32, 12), 512, 0, stream>>>(
      xn, wqkv_t, nullptr, qkv_b, out_k, 4096, 3072, 1024, 1024, 1024);
  k_vtrans<<<dim3(32, 64), 256, 0, stream>>>(qkv_b, 3072, 2048, vTsa, 1024, 1024);
  k_attn4<true><<<dim3(8, 64), 512, 0, stream>>>(
      qkv_b, 3072, qkv_b + 1024, 3072, vTsa, 1024,
      sa_b, 1024, nullptr, 0, 1024, 1024, 0.125f);
  // wo_sa: 128x64 tile, no split, residual fused -> x1; then LN -> qn
  k_gemm5<true, true, false><<<dim3(32, 16), 256, 0, stream>>>(
      sa_b, wosa_t, x1, nullptr, x, 4096, 1024, 1024, 1024, 1024);
  k_ln<<<4096, 256, 0, stream>>>(x1, g_xaq, qn);

  // --- cross-attention block ---
  // wq: 128x64 tile, bf16 out direct
  k_gemm5<false, false, true><<<dim3(32, 16), 256, 0, stream>>>(
      qn, wq_t, nullptr, qx_b, nullptr, 4096, 1024, 1024, 1024, 1024);
  k_gemm4<false, false, true, false><<<dim3(47, 8), 512, 0, stream>>>(
      mn, wkv_t, nullptr, kvx_b, nullptr, 6000, 2048, 1024, 1024, 1024);
  k_vtrans<<<dim3(48, 64), 256, 0, stream>>>(kvx_b, 2048, 1024, vTxa, 1500, 1536);
  k_attn4<false><<<dim3(8, 64), 512, 0, stream>>>(
      qx_b, 1024, kvx_b, 2048, vTxa, 1536,
      xa_b, 1024, mbits, 24, 1024, 1500, 0.125f);
  // wo_xa: residual fused -> x2; then LN -> hn
  k_gemm5<true, true, false><<<dim3(32, 16), 256, 0, stream>>>(
      xa_b, woxa_t, x2, nullptr, x1, 4096, 1024, 1024, 1024, 1024);
  k_ln<<<4096, 256, 0, stream>>>(x2, g_ff, hn);

  // --- FFN block ---
  k_gemm4<true, false, true, false><<<dim3(32, 16), 512, 0, stream>>>(
      hn, wff1_t, nullptr, h1, nullptr, 4096, 4096, 1024, 1024, 1024);
  // ff2: 128x64 tile, K=4096, no split, residual fused, writes out_x directly
  k_gemm5<true, true, false><<<dim3(32, 16), 256, 0, stream>>>(
      h1, wff2_t, out_x, nullptr, x2, 4096, 1024, 4096, 4096, 4096);
}

// Round 14
// 384.222 us; speedup vs baseline: 1.0087x; 1.0087x over previous
//
#include <hip/hip_runtime.h>
#include <hip/hip_bf16.h>
#include <cstdint>
#include <cstddef>

// ---------------------------------------------------------------------------
// PrefillDecoderLayer on MI355X (gfx950).
// Fat GEMMs (qkv/wkv/ff1/ff2): 128x256 tile, 8 waves, BK=64, 48KB LDS;
// ff2 split-K x4 (2 blocks/CU) + fused-residual reduce.
// Skinny GEMMs (wo_*/wq): 128x64 tile, 4 waves, 24KB LDS, no split,
// residual/bf16 fused. All single-buffered, hoisted staging, XOR-swizzled
// LDS, banded XCD swizzle.
// Flash attention v6 (KVBLK=64, raw-score max + folded scale, v_max3,
// defer-max, head-banded XCD locality); SA unpaired heavy-first.
// ---------------------------------------------------------------------------

typedef __attribute__((ext_vector_type(4))) float f32x4;
typedef __attribute__((ext_vector_type(8))) short s8v;   // 8 bf16 as raw bits
typedef __attribute__((ext_vector_type(2))) unsigned uint2v;

#define DEVI __device__ __forceinline__

DEVI short f2bf(float f) {  // RNE float -> bf16 bits
  union { float f; unsigned u; } x; x.f = f;
  unsigned r = x.u + 0x7fffu + ((x.u >> 16) & 1u);
  return (short)(r >> 16);
}
DEVI unsigned cvtpk_bf2(float lo, float hi) {  // v_cvt_pk_bf16_f32 (RNE)
  unsigned r;
  asm("v_cvt_pk_bf16_f32 %0, %1, %2" : "=v"(r) : "v"(lo), "v"(hi));
  return r;
}
DEVI float fexp2(float x) {
  float r;
  asm("v_exp_f32 %0, %1" : "=v"(r) : "v"(x));
  return r;
}
DEVI float fmax3(float a, float b, float c) {
  float r;
  asm("v_max3_f32 %0, %1, %2, %3" : "=v"(r) : "v"(a), "v"(b), "v"(c));
  return r;
}
DEVI float bpermf(int srclane, float v) {
  union { float f; int i; } x; x.f = v;
  x.i = __builtin_amdgcn_ds_bpermute(srclane << 2, x.i);
  return x.f;
}
DEVI void gload_lds16(const void* g, void* l) {
  __builtin_amdgcn_global_load_lds((const __attribute__((address_space(1))) void*)g,
                                   (__attribute__((address_space(3))) void*)l,
                                   16, 0, 0);
}

// banded XCD swizzle: XCD-major linear id, 8-wide bx bands, col-major
DEVI void xcd_swizzle(int& bx, int& by) {
  int gx = gridDim.x, gy = gridDim.y;
  int nxy = gx * gy, chunk = nxy >> 3;
  int orig = blockIdx.y * gx + blockIdx.x;
  int gid = (orig & 7) * chunk + (orig >> 3);
  int full = gy << 3, nfull = gx >> 3, lim = nfull * full;
  if (gid < lim) {
    int band = gid / full, r = gid - band * full;
    bx = (band << 3) + (r & 7);
    by = r >> 3;
  } else {
    int r = gid - lim, w = gx - (nfull << 3);
    bx = (nfull << 3) + r % w;
    by = r / w;
  }
}

// ---------------------------------------------------------------------------
// Prep uber-kernel: 7 weight transposes (fp32 KxN -> bf16 NxK) + maskpack.
// ---------------------------------------------------------------------------
__global__ __launch_bounds__(256) void k_prep(
    const float* __restrict__ wqkv, const float* __restrict__ wosa,
    const float* __restrict__ wq,   const float* __restrict__ wkv,
    const float* __restrict__ woxa, const float* __restrict__ wff1,
    const float* __restrict__ wff2,
    short* __restrict__ wqkv_t, short* __restrict__ wosa_t,
    short* __restrict__ wq_t,   short* __restrict__ wkv_t,
    short* __restrict__ woxa_t, short* __restrict__ wff1_t,
    short* __restrict__ wff2_t,
    const int* __restrict__ mask, unsigned long long* __restrict__ mbits) {
  int id = blockIdx.x;
  const float* w; short* wt; int K, N, tx, r;
  if (id < 3072)       { w = wqkv; wt = wqkv_t; K = 1024; N = 3072; tx = 96;  r = id; }
  else if (id < 4096)  { w = wosa; wt = wosa_t; K = 1024; N = 1024; tx = 32;  r = id - 3072; }
  else if (id < 5120)  { w = wq;   wt = wq_t;   K = 1024; N = 1024; tx = 32;  r = id - 4096; }
  else if (id < 7168)  { w = wkv;  wt = wkv_t;  K = 1024; N = 2048; tx = 64;  r = id - 5120; }
  else if (id < 8192)  { w = woxa; wt = woxa_t; K = 1024; N = 1024; tx = 32;  r = id - 7168; }
  else if (id < 12288) { w = wff1; wt = wff1_t; K = 1024; N = 4096; tx = 128; r = id - 8192; }
  else if (id < 16384) { w = wff2; wt = wff2_t; K = 4096; N = 1024; tx = 32;  r = id - 12288; }
  else {
    int t = threadIdx.x;
    if (t < 96) {
      int b = t / 24, wd = t % 24;
      unsigned long long v = 0;
      const int* mb = mask + (size_t)b * 1500;
      for (int j = 0; j < 64; j++) {
        int k = wd * 64 + j;
        if (k < 1500 && mb[k]) v |= (1ull << j);
      }
      mbits[b * 24 + wd] = v;
    }
    return;
  }
  __shared__ float tile[32][33];
  int n0 = (r % tx) * 32, k0 = (r / tx) * 32;
  int t = threadIdx.x;
  int row = t >> 3, c4 = (t & 7) * 4;
  *(f32x4*)&tile[row][c4] = *(const f32x4*)(w + (size_t)(k0 + row) * N + n0 + c4);
  __syncthreads();
  float v0 = tile[c4 + 0][row], v1 = tile[c4 + 1][row];
  float v2 = tile[c4 + 2][row], v3 = tile[c4 + 3][row];
  uint2v o = {cvtpk_bf2(v0, v1), cvtpk_bf2(v2, v3)};
  *(uint2v*)(wt + (size_t)(n0 + row) * K + k0 + c4) = o;
}

// ---------------------------------------------------------------------------
// Per-head V transpose: src[b*T+t][coff+h*64+d] -> dst[(b*16+h)][64][Tp]
// ---------------------------------------------------------------------------
__global__ __launch_bounds__(256) void k_vtrans(
    const short* __restrict__ src, int srs, int coff,
    short* __restrict__ dst, int T, int Tp) {
  __shared__ short tile[32][72];
  int bh = blockIdx.y, b = bh >> 4, h = bh & 15;
  int t0 = blockIdx.x * 32;
  const short* sB = src + (size_t)b * T * srs + coff + h * 64;
  short* dB = dst + (size_t)bh * 64 * Tp;
  int t = threadIdx.x;
  int r = t >> 3, c = (t & 7) * 8;
  int tr = t0 + r; if (tr > T - 1) tr = T - 1;
  *(s8v*)&tile[r][c] = *(const s8v*)(sB + (size_t)tr * srs + c);
  __syncthreads();
  int d = t & 63, ch = t >> 6;
  s8v o;
#pragma unroll
  for (int j = 0; j < 8; j++) o[j] = tile[ch * 8 + j][d];
  *(s8v*)(dB + (size_t)d * Tp + t0 + ch * 8) = o;
}

// ---------------------------------------------------------------------------
// Dual LayerNorm (x: 4096 rows -> xn; enc: 6000 rows -> mn), D=1024.
// ---------------------------------------------------------------------------
__global__ __launch_bounds__(256) void k_ln2(
    const float* __restrict__ x, const float* __restrict__ gx,
    short* __restrict__ ox,
    const float* __restrict__ e, const float* __restrict__ ge,
    short* __restrict__ oe) {
  int id = blockIdx.x;
  const float* src; const float* g; short* dst; int row;
  if (id < 4096) { src = x; g = gx; dst = ox; row = id; }
  else           { src = e; g = ge; dst = oe; row = id - 4096; }
  const float* xr = src + (size_t)row * 1024;
  int t = threadIdx.x, wid = t >> 6, lane = t & 63;
  f32x4 v = ((const f32x4*)xr)[t];
  float s = v[0] + v[1] + v[2] + v[3];
#pragma unroll
  for (int m = 32; m >= 1; m >>= 1) s += __shfl_xor(s, m);
  __shared__ float red[4];
  if (lane == 0) red[wid] = s;
  __syncthreads();
  float mean = (red[0] + red[1] + red[2] + red[3]) * (1.f / 1024.f);
  float q = 0.f;
#pragma unroll
  for (int i = 0; i < 4; i++) { v[i] -= mean; q += v[i] * v[i]; }
#pragma unroll
  for (int m = 32; m >= 1; m >>= 1) q += __shfl_xor(q, m);
  __syncthreads();
  if (lane == 0) red[wid] = q;
  __syncthreads();
  float var = (red[0] + red[1] + red[2] + red[3]) * (1.f / 1024.f);
  float rs = rsqrtf(var + 1e-5f);
  f32x4 gv = ((const f32x4*)g)[t];
  uint2v w = {cvtpk_bf2(v[0] * rs * gv[0], v[1] * rs * gv[1]),
              cvtpk_bf2(v[2] * rs * gv[2], v[3] * rs * gv[3])};
  *(uint2v*)(dst + (size_t)row * 1024 + t * 4) = w;
}

// single LayerNorm, D=1024, fp32 -> bf16
__global__ __launch_bounds__(256) void k_ln(
    const float* __restrict__ x, const float* __restrict__ g,
    short* __restrict__ out) {
  int row = blockIdx.x;
  const float* xr = x + (size_t)row * 1024;
  int t = threadIdx.x, wid = t >> 6, lane = t & 63;
  f32x4 v = ((const f32x4*)xr)[t];
  float s = v[0] + v[1] + v[2] + v[3];
#pragma unroll
  for (int m = 32; m >= 1; m >>= 1) s += __shfl_xor(s, m);
  __shared__ float red[4];
  if (lane == 0) red[wid] = s;
  __syncthreads();
  float mean = (red[0] + red[1] + red[2] + red[3]) * (1.f / 1024.f);
  float q = 0.f;
#pragma unroll
  for (int i = 0; i < 4; i++) { v[i] -= mean; q += v[i] * v[i]; }
#pragma unroll
  for (int m = 32; m >= 1; m >>= 1) q += __shfl_xor(q, m);
  __syncthreads();
  if (lane == 0) red[wid] = q;
  __syncthreads();
  float var = (red[0] + red[1] + red[2] + red[3]) * (1.f / 1024.f);
  float rs = rsqrtf(var + 1e-5f);
  f32x4 gv = ((const f32x4*)g)[t];
  uint2v w = {cvtpk_bf2(v[0] * rs * gv[0], v[1] * rs * gv[1]),
              cvtpk_bf2(v[2] * rs * gv[2], v[3] * rs * gv[3])};
  *(uint2v*)(out + (size_t)row * 1024 + t * 4) = w;
}

// ---------------------------------------------------------------------------
// GEMM v4 (fat): 128x256 tile, BK=64, 8 waves (2Mx4N), 48KB LDS (3 blk/CU).
// blockIdx.z = split-K slice (fp32 partial slabs when F32OUT&&SPLIT).
// ---------------------------------------------------------------------------
template <bool GELU_, bool F32OUT, bool BF16OUT, bool KV, bool SPLIT>
__global__ __launch_bounds__(512) void k_gemm4(
    const short* __restrict__ A, const short* __restrict__ Bt,
    float* __restrict__ Cf, short* __restrict__ Cb,
    float* __restrict__ okv, int M, int N, int K, int lda, int ldb) {
  __shared__ short As[128 * 64];   // 16 KB
  __shared__ short Bs[256 * 64];   // 32 KB
  if (SPLIT) {
    int z = blockIdx.z;
    A += (size_t)z * K;
    Bt += (size_t)z * K;
    if (F32OUT) Cf += (size_t)z * (size_t)M * N;
  }

  int bx, by;
  xcd_swizzle(bx, by);
  int am = bx * 128, bn = by * 256;

  int t = threadIdx.x, wid = t >> 6, lane = t & 63;
  int la = lane & 15, lb = lane >> 4;
  int wr = wid >> 2, wc = wid & 3;

  const short* gpA[2]; const short* gpB[4];
  int dofA[2], dofB[4];
#pragma unroll
  for (int l = 0; l < 2; l++) {
    int c = l * 512 + t;
    int row = c >> 3, g = c & 7;
    int ar = am + row; if (ar > M - 1) ar = M - 1;
    gpA[l] = A + (size_t)ar * lda + ((g ^ (row & 7)) << 3);
    dofA[l] = (l * 512 + wid * 64) * 8;
  }
#pragma unroll
  for (int l = 0; l < 4; l++) {
    int c = l * 512 + t;
    int row = c >> 3, g = c & 7;
    gpB[l] = Bt + (size_t)(bn + row) * ldb + ((g ^ (row & 7)) << 3);
    dofB[l] = (l * 512 + wid * 64) * 8;
  }

  int aOff[4], bOff[4];
#pragma unroll
  for (int m = 0; m < 4; m++) {
    int r = wr * 64 + m * 16 + la;
    aOff[m] = r * 64 + ((lb ^ (r & 7)) << 3);
  }
#pragma unroll
  for (int n = 0; n < 4; n++) {
    int r = wc * 64 + n * 16 + la;
    bOff[n] = r * 64 + ((lb ^ (r & 7)) << 3);
  }

  f32x4 acc[4][4];
#pragma unroll
  for (int m = 0; m < 4; m++)
#pragma unroll
    for (int n = 0; n < 4; n++) acc[m][n] = (f32x4){0.f, 0.f, 0.f, 0.f};

  int nk = K >> 6;
  for (int ks = 0; ks < nk; ++ks) {
#pragma unroll
    for (int l = 0; l < 2; l++) { gload_lds16(gpA[l], As + dofA[l]); gpA[l] += 64; }
#pragma unroll
    for (int l = 0; l < 4; l++) { gload_lds16(gpB[l], Bs + dofB[l]); gpB[l] += 64; }
    __syncthreads();
#pragma unroll
    for (int kk = 0; kk < 2; kk++) {
      s8v af[4], bfg[4];
#pragma unroll
      for (int m = 0; m < 4; m++)
        af[m] = *(const s8v*)(As + (aOff[m] ^ (kk << 5)));
#pragma unroll
      for (int n = 0; n < 4; n++)
        bfg[n] = *(const s8v*)(Bs + (bOff[n] ^ (kk << 5)));
#pragma unroll
      for (int m = 0; m < 4; m++)
#pragma unroll
        for (int n = 0; n < 4; n++)
          acc[m][n] = __builtin_amdgcn_mfma_f32_16x16x32_bf16(af[m], bfg[n], acc[m][n], 0, 0, 0);
    }
    __syncthreads();
  }

#pragma unroll
  for (int m = 0; m < 4; m++) {
    int rb = am + wr * 64 + m * 16 + lb * 4;
#pragma unroll
    for (int n = 0; n < 4; n++) {
      int col = bn + wc * 64 + n * 16 + la;
#pragma unroll
      for (int j = 0; j < 4; j++) {
        int r = rb + j;
        if (r < M) {
          float v = acc[m][n][j];
          if (GELU_) {
            float u = v;
            float y = 0.7978845608f * u * (1.f + 0.044715f * u * u);
            float e = fexp2(fminf(y * 2.88539008f, 80.f));  // e^{2y}
            float th = (e - 1.f) * __builtin_amdgcn_rcpf(e + 1.f);
            v = 0.5f * u * (1.f + th);
          }
          if (F32OUT) Cf[(size_t)r * N + col] = v;
          if (BF16OUT) Cb[(size_t)r * N + col] = f2bf(v);
          if (KV) {  // fused fp32 k/v export (qkv GEMM)
            if (col >= 2048)
              okv[(size_t)4096 * 1024 + (size_t)r * 1024 + (col - 2048)] = v;
            else if (col >= 1024)
              okv[(size_t)r * 1024 + (col - 1024)] = v;
          }
        }
      }
    }
  }
}

// ---------------------------------------------------------------------------
// GEMM v5 (narrow): 128x64 tile, BK=64, 4 waves (2Mx2N), 24KB LDS, no split.
// Residual / bf16-out fused in epilogue.
// ---------------------------------------------------------------------------
template <bool RES, bool F32OUT, bool BF16OUT>
__global__ __launch_bounds__(256) void k_gemm5(
    const short* __restrict__ A, const short* __restrict__ Bt,
    float* __restrict__ Cf, short* __restrict__ Cb,
    const float* __restrict__ res, int M, int N, int K, int lda, int ldb) {
  __shared__ short As[128 * 64];   // 16 KB
  __shared__ short Bs[64 * 64];    //  8 KB

  int bx, by;
  xcd_swizzle(bx, by);
  int am = bx * 128, bn = by * 64;

  int t = threadIdx.x, wid = t >> 6, lane = t & 63;
  int la = lane & 15, lb = lane >> 4;
  int wr = wid >> 1, wc = wid & 1;

  const short* gpA[4]; const short* gpB[2];
  int dofA[4], dofB[2];
#pragma unroll
  for (int l = 0; l < 4; l++) {
    int cl = l * 256 + t;
    int row = cl >> 3, g = cl & 7;
    int ar = am + row; if (ar > M - 1) ar = M - 1;
    gpA[l] = A + (size_t)ar * lda + ((g ^ (row & 7)) << 3);
    dofA[l] = (l * 256 + wid * 64) * 8;
  }
#pragma unroll
  for (int l = 0; l < 2; l++) {
    int cl = l * 256 + t;
    int row = cl >> 3, g = cl & 7;
    gpB[l] = Bt + (size_t)(bn + row) * ldb + ((g ^ (row & 7)) << 3);
    dofB[l] = (l * 256 + wid * 64) * 8;
  }

  int aOff[4], bOff[2];
#pragma unroll
  for (int m = 0; m < 4; m++) {
    int r = wr * 64 + m * 16 + la;
    aOff[m] = r * 64 + ((lb ^ (r & 7)) << 3);
  }
#pragma unroll
  for (int n = 0; n < 2; n++) {
    int r = wc * 32 + n * 16 + la;
    bOff[n] = r * 64 + ((lb ^ (r & 7)) << 3);
  }

  f32x4 acc[4][2];
#pragma unroll
  for (int m = 0; m < 4; m++)
#pragma unroll
    for (int n = 0; n < 2; n++) acc[m][n] = (f32x4){0.f, 0.f, 0.f, 0.f};

  int nk = K >> 6;
  for (int ks = 0; ks < nk; ++ks) {
#pragma unroll
    for (int l = 0; l < 4; l++) { gload_lds16(gpA[l], As + dofA[l]); gpA[l] += 64; }
#pragma unroll
    for (int l = 0; l < 2; l++) { gload_lds16(gpB[l], Bs + dofB[l]); gpB[l] += 64; }
    __syncthreads();
#pragma unroll
    for (int kk = 0; kk < 2; kk++) {
      s8v af[4], bfg[2];
#pragma unroll
      for (int m = 0; m < 4; m++)
        af[m] = *(const s8v*)(As + (aOff[m] ^ (kk << 5)));
#pragma unroll
      for (int n = 0; n < 2; n++)
        bfg[n] = *(const s8v*)(Bs + (bOff[n] ^ (kk << 5)));
#pragma unroll
      for (int m = 0; m < 4; m++)
#pragma unroll
        for (int n = 0; n < 2; n++)
          acc[m][n] = __builtin_amdgcn_mfma_f32_16x16x32_bf16(af[m], bfg[n], acc[m][n], 0, 0, 0);
    }
    __syncthreads();
  }

#pragma unroll
  for (int m = 0; m < 4; m++) {
    int rb = am + wr * 64 + m * 16 + lb * 4;
#pragma unroll
    for (int n = 0; n < 2; n++) {
      int col = bn + wc * 32 + n * 16 + la;
#pragma unroll
      for (int j = 0; j < 4; j++) {
        int r = rb + j;
        if (r < M) {
          float v = acc[m][n][j];
          if (RES) v += res[(size_t)r * N + col];
          if (F32OUT) Cf[(size_t)r * N + col] = v;
          if (BF16OUT) Cb[(size_t)r * N + col] = f2bf(v);
        }
      }
    }
  }
}

// split-K x4 reduce + residual -> fp32 out (ff2)
__global__ __launch_bounds__(256) void k_red4(
    const f32x4* __restrict__ p, const f32x4* __restrict__ res,
    float* __restrict__ outf, int n) {
  int i = blockIdx.x * 256 + threadIdx.x;
  f32x4 v = res[i] + ((p[i] + p[i + (size_t)n]) +
                      (p[i + 2 * (size_t)n] + p[i + 3 * (size_t)n]));
  ((f32x4*)outf)[i] = v;
}

// ---------------------------------------------------------------------------
// Flash attention v6. 512 thr = 8 waves x 16 q-rows = 128 q/block.
// CAUSAL: 512 blocks, ONE supertile each, heavy-first (st = 7 - qsel).
// XA: 512 blocks (qsel 0..7). Raw-score max + folded scale, v_max3 tree,
// defer-max, head-banded XCD locality.
// ---------------------------------------------------------------------------
template <bool CAUSAL>
__global__ __launch_bounds__(512) void k_attn4(
    const short* __restrict__ qbuf, int qrs,
    const short* __restrict__ kbuf, int krs,
    const short* __restrict__ vT, int vts,
    short* __restrict__ obuf, int ors,
    const unsigned long long* __restrict__ mbits, int mwords,
    int Tq, int Tk, float scale) {
  __shared__ short Ks[64 * 64];
  __shared__ short Vs[64 * 64];
  __shared__ short Ps[8 * 1024];
  int lid = blockIdx.y * gridDim.x + blockIdx.x;
  int rest = lid >> 3;
  int bh = (lid & 7) * 8 + (rest & 7);
  int qsel = rest >> 3;                 // 0..7
  int st = CAUSAL ? (7 - qsel) : qsel;  // heavy supertiles dispatch first
  int b = bh >> 4, h = bh & 15;
  int t = threadIdx.x, wid = t >> 6, lane = t & 63;
  int la = lane & 15, lb = lane >> 4;
  float lscale = scale * 1.44269504f;   // log2 domain

  const short* qB = qbuf + (size_t)b * Tq * qrs + h * 64;
  const short* kB = kbuf + (size_t)b * Tk * krs + h * 64;
  const short* vB = vT + (size_t)bh * 64 * vts;
  char* Pw = (char*)(Ps + wid * 1024);

  int sr = t >> 3, scol = (t & 7) * 8;
  int swz = sr * 64 + (scol ^ ((sr & 7) << 3));

  int q0 = st * 128 + wid * 16;
  int nkt = CAUSAL ? 2 * st + 2 : (Tk + 63) >> 6;
  int lastkt = CAUSAL ? (q0 >> 6) : nkt - 1;

  s8v qf[2];
#pragma unroll
  for (int kk = 0; kk < 2; kk++)
    qf[kk] = *(const s8v*)(qB + (size_t)(q0 + la) * qrs + kk * 32 + lb * 8);

  f32x4 accO[4];
#pragma unroll
  for (int n = 0; n < 4; n++) accO[n] = (f32x4){0.f, 0.f, 0.f, 0.f};
  float m = -1e30f, l = 0.f;

  s8v krg, vrg;
  {
    int tk = sr; if (tk > Tk - 1) tk = Tk - 1;
    krg = *(const s8v*)(kB + (size_t)tk * krs + scol);
    vrg = *(const s8v*)(vB + (size_t)sr * vts + scol);
  }

  for (int kt = 0; kt < nkt; kt++) {
    int kb0 = kt << 6;
    __syncthreads();
    *(s8v*)&Ks[swz] = krg;
    *(s8v*)&Vs[swz] = vrg;
    __syncthreads();
    if (kt + 1 < nkt) {
      int kb = kb0 + 64;
      int tk = kb + sr; if (tk > Tk - 1) tk = Tk - 1;
      krg = *(const s8v*)(kB + (size_t)tk * krs + scol);
      vrg = *(const s8v*)(vB + (size_t)sr * vts + kb + scol);
    }
    if (kt > lastkt) continue;

    bool needMask;
    unsigned long long wm = ~0ull;
    if (CAUSAL) {
      needMask = (kt == lastkt);
    } else {
      wm = mbits[(size_t)b * mwords + kt];
      needMask = (wm != ~0ull);
    }

    // QK^T raw scores: lane holds S_raw[q=la][k=16n+lb*4+j]
    float sc[4][4];
    __builtin_amdgcn_s_setprio(1);
#pragma unroll
    for (int n = 0; n < 4; n++) {
      f32x4 a = (f32x4){0.f, 0.f, 0.f, 0.f};
#pragma unroll
      for (int kk = 0; kk < 2; kk++) {
        s8v kf = *(const s8v*)&Ks[(n * 16 + la) * 64 +
                                  ((kk * 32 + lb * 8) ^ ((la & 7) << 3))];
        a = __builtin_amdgcn_mfma_f32_16x16x32_bf16(kf, qf[kk], a, 0, 0, 0);
      }
      if (needMask) {
#pragma unroll
        for (int j = 0; j < 4; j++) {
          int ki = n * 16 + lb * 4 + j;
          bool ok = CAUSAL ? (kb0 + ki <= q0 + la) : (((wm >> ki) & 1ull) != 0);
          sc[n][j] = ok ? a[j] : -1e30f;
        }
      } else {
#pragma unroll
        for (int j = 0; j < 4; j++) sc[n][j] = a[j];
      }
    }
    __builtin_amdgcn_s_setprio(0);

    // raw-score max via v_max3 tree; scale applied once after reduce
    float rn[4];
#pragma unroll
    for (int n = 0; n < 4; n++)
      rn[n] = fmaxf(fmax3(sc[n][0], sc[n][1], sc[n][2]), sc[n][3]);
    float tm = fmaxf(fmax3(rn[0], rn[1], rn[2]), rn[3]);
    tm = fmaxf(tm, __shfl_xor(tm, 16));
    tm = fmaxf(tm, __shfl_xor(tm, 32));
    tm = fmaxf(tm * lscale, -1e4f);

    bool skip = __all(tm - m <= 10.f);  // defer-max (T13)
    float alpha = 1.f;
    if (!skip) {
      float mn_ = fmaxf(m, tm);
      alpha = fexp2(m - mn_);
      m = mn_;
    }
    float nm = -m;

    unsigned W[4][2];
    float ps = 0.f;
#pragma unroll
    for (int n = 0; n < 4; n++) {
      float p0 = fexp2(__builtin_fmaf(sc[n][0], lscale, nm));
      float p1 = fexp2(__builtin_fmaf(sc[n][1], lscale, nm));
      float p2 = fexp2(__builtin_fmaf(sc[n][2], lscale, nm));
      float p3 = fexp2(__builtin_fmaf(sc[n][3], lscale, nm));
      ps += (p0 + p1) + (p2 + p3);
      W[n][0] = cvtpk_bf2(p0, p1);
      W[n][1] = cvtpk_bf2(p2, p3);
    }
    ps += __shfl_xor(ps, 16);
    ps += __shfl_xor(ps, 32);
    l = l * alpha + ps;

    if (!skip) {
#pragma unroll
      for (int j = 0; j < 4; j++) {
        float aj = bpermf(lb * 20 + j, alpha);
#pragma unroll
        for (int n = 0; n < 4; n++) accO[n][j] *= aj;
      }
    }

#pragma unroll
    for (int n = 0; n < 4; n++) {
      uint2v w2 = {W[n][0], W[n][1]};
      *(uint2v*)(Pw + ((la * 128 + n * 32 + lb * 8) ^ ((la & 7) << 4))) = w2;
    }
    __builtin_amdgcn_s_setprio(1);
#pragma unroll
    for (int kk = 0; kk < 2; kk++) {
      s8v pa = *(const s8v*)(Pw + ((la * 128 + kk * 64 + lb * 16) ^ ((la & 7) << 4)));
#pragma unroll
      for (int n = 0; n < 4; n++) {
        s8v vf = *(const s8v*)&Vs[(n * 16 + la) * 64 +
                                  ((kk * 32 + lb * 8) ^ ((la & 7) << 3))];
        accO[n] = __builtin_amdgcn_mfma_f32_16x16x32_bf16(pa, vf, accO[n], 0, 0, 0);
      }
    }
    __builtin_amdgcn_s_setprio(0);
  }

#pragma unroll
  for (int j = 0; j < 4; j++) {
    float lj = bpermf(lb * 20 + j, l);
    float inv = 1.f / lj;
    int r = q0 + lb * 4 + j;
#pragma unroll
    for (int n = 0; n < 4; n++)
      obuf[(size_t)(b * Tq + r) * ors + h * 64 + n * 16 + la] = f2bf(accO[n][j] * inv);
  }
}

// ---------------------------------------------------------------------------
extern "C" void kernel_launch(void* const* d_in, const int* in_sizes, int n_in,
                              void* d_out, int out_size, void* d_ws, size_t ws_size,
                              hipStream_t stream) {
  (void)in_sizes; (void)n_in; (void)out_size; (void)ws_size;
  const float* x      = (const float*)d_in[0];
  const float* enc    = (const float*)d_in[1];
  const int*   mask   = (const int*)d_in[2];
  const float* w_qkv  = (const float*)d_in[3];
  const float* w_o_sa = (const float*)d_in[4];
  const float* w_q    = (const float*)d_in[5];
  const float* w_kv   = (const float*)d_in[6];
  const float* w_o_xa = (const float*)d_in[7];
  const float* w_ff1  = (const float*)d_in[8];
  const float* w_ff2  = (const float*)d_in[9];
  const float* g_sa   = (const float*)d_in[10];
  const float* g_xaq  = (const float*)d_in[11];
  const float* g_xam  = (const float*)d_in[12];
  const float* g_ff   = (const float*)d_in[13];

  float* out_x = (float*)d_out;
  float* out_k = out_x + (size_t)4096 * 1024;

  char* ws = (char*)d_ws;
  size_t off = 0;
  auto alloc = [&](size_t bytes) -> void* {
    void* p = ws + off;
    off += (bytes + 255) & ~(size_t)255;
    return p;
  };
  short* wqkv_t = (short*)alloc((size_t)3072 * 1024 * 2);
  short* wosa_t = (short*)alloc((size_t)1024 * 1024 * 2);
  short* wq_t   = (short*)alloc((size_t)1024 * 1024 * 2);
  short* wkv_t  = (short*)alloc((size_t)2048 * 1024 * 2);
  short* woxa_t = (short*)alloc((size_t)1024 * 1024 * 2);
  short* wff1_t = (short*)alloc((size_t)4096 * 1024 * 2);
  short* wff2_t = (short*)alloc((size_t)1024 * 4096 * 2);
  short* xn     = (short*)alloc((size_t)4096 * 1024 * 2);  // reused as vTsa
  short* qkv_b  = (short*)alloc((size_t)4096 * 3072 * 2);  // + ff2 partial slab
  short* sa_b   = (short*)alloc((size_t)4096 * 1024 * 2);  //   (spans qkv_b..mn)
  float* x1     = (float*)alloc((size_t)4096 * 1024 * 4);
  short* qn     = (short*)alloc((size_t)4096 * 1024 * 2);
  short* mn     = (short*)alloc((size_t)6000 * 1024 * 2);
  short* qx_b   = (short*)alloc((size_t)4096 * 1024 * 2);
  short* kvx_b  = (short*)alloc((size_t)6000 * 2048 * 2);
  short* xa_b   = (short*)alloc((size_t)4096 * 1024 * 2);
  float* x2     = (float*)alloc((size_t)4096 * 1024 * 4);
  short* hn     = (short*)alloc((size_t)4096 * 1024 * 2);
  short* h1     = (short*)alloc((size_t)4096 * 4096 * 2);  // first 12.6MB = vTxa
  unsigned long long* mbits = (unsigned long long*)alloc(4 * 24 * 8);

  short* vTsa = xn;            // [64 bh][64][1024]
  short* vTxa = h1;            // [64 bh][64][1536]
  float* partQ = (float*)qkv_b;// 64MB ff2 partials (qkv_b..mn dead in FFN)
  const int NRED = 1048576;    // 4096*1024/4 f32x4 elements per slice

  // prep: all weight transposes + maskpack in one launch
  k_prep<<<16385, 256, 0, stream>>>(
      w_qkv, w_o_sa, w_q, w_kv, w_o_xa, w_ff1, w_ff2,
      wqkv_t, wosa_t, wq_t, wkv_t, woxa_t, wff1_t, wff2_t, mask, mbits);
  // LN(x) + LN(enc) in one launch
  k_ln2<<<10096, 256, 0, stream>>>(x, g_sa, xn, enc, g_xam, mn);

  // --- self-attention block ---
  k_gemm4<false, false, true, true, false><<<dim3(32, 12), 512, 0, stream>>>(
      xn, wqkv_t, nullptr, qkv_b, out_k, 4096, 3072, 1024, 1024, 1024);
  k_vtrans<<<dim3(32, 64), 256, 0, stream>>>(qkv_b, 3072, 2048, vTsa, 1024, 1024);
  k_attn4<true><<<dim3(8, 64), 512, 0, stream>>>(
      qkv_b, 3072, qkv_b + 1024, 3072, vTsa, 1024,
      sa_b, 1024, nullptr, 0, 1024, 1024, 0.125f);
  // wo_sa: 128x64 tile, no split, residual fused -> x1; then LN -> qn
  k_gemm5<true, true, false><<<dim3(32, 16), 256, 0, stream>>>(
      sa_b, wosa_t, x1, nullptr, x, 4096, 1024, 1024, 1024, 1024);
  k_ln<<<4096, 256, 0, stream>>>(x1, g_xaq, qn);

  // --- cross-attention block ---
  // wq: 128x64 tile, bf16 out direct
  k_gemm5<false, false, true><<<dim3(32, 16), 256, 0, stream>>>(
      qn, wq_t, nullptr, qx_b, nullptr, 4096, 1024, 1024, 1024, 1024);
  k_gemm4<false, false, true, false, false><<<dim3(47, 8), 512, 0, stream>>>(
      mn, wkv_t, nullptr, kvx_b, nullptr, 6000, 2048, 1024, 1024, 1024);
  k_vtrans<<<dim3(48, 64), 256, 0, stream>>>(kvx_b, 2048, 1024, vTxa, 1500, 1536);
  k_attn4<false><<<dim3(8, 64), 512, 0, stream>>>(
      qx_b, 1024, kvx_b, 2048, vTxa, 1536,
      xa_b, 1024, mbits, 24, 1024, 1500, 0.125f);
  // wo_xa: residual fused -> x2; then LN -> hn
  k_gemm5<true, true, false><<<dim3(32, 16), 256, 0, stream>>>(
      xa_b, woxa_t, x2, nullptr, x1, 4096, 1024, 1024, 1024, 1024);
  k_ln<<<4096, 256, 0, stream>>>(x2, g_ff, hn);

  // --- FFN block ---
  k_gemm4<true, false, true, false, false><<<dim3(32, 16), 512, 0, stream>>>(
      hn, wff1_t, nullptr, h1, nullptr, 4096, 4096, 1024, 1024, 1024);
  // ff2: 128x256 split-K x4 (K=1024 each, 2 blk/CU) -> 64MB partials, reduce
  k_gemm4<false, true, false, false, true><<<dim3(32, 4, 4), 512, 0, stream>>>(
      h1, wff2_t, partQ, nullptr, nullptr, 4096, 1024, 1024, 4096, 4096);
  k_red4<<<4096, 256, 0, stream>>>(
      (const f32x4*)partQ, (const f32x4*)x2, out_x, NRED);
}